// Round 3
// baseline (5570.163 us; speedup 1.0000x reference)
//
#include <hip/hip_runtime.h>
#include <math.h>

#define NPTS  65536
#define DIM   256
#define NC    512
#define NITER 10

// ---------------- workspace layout (float offsets) ----------------
#define WS_C      0                       // clusters        512*256
#define WS_WSUM   (WS_C + NC*DIM)         // weighted sums   512*256
#define WS_COUNTS (WS_WSUM + NC*DIM)      // counts          512
#define WS_W2     (WS_COUNTS + NC)        // ||w||^2         65536
#define WS_C2     (WS_W2 + NPTS)          // ||c||^2         512
#define WS_DONE   (WS_C2 + NC)            // done flag (int)

// XOR swizzles: transpose-staged LDS tiles, conflict-free vector reads.
__device__ __forceinline__ int swz32(int k, int r) {   // [k][32] rows, b64 reads at r=2*ty
  return (k << 5) + (r ^ (((k >> 2) & 15) << 1));
}
__device__ __forceinline__ int swz64(int k, int c) {   // [k][64] rows, b128 reads at c=4*tx
  return (k << 6) + (c ^ (((k >> 2) & 15) << 2));
}

// ---------------- init: C = W[0:512], done = 0 ----------------
__global__ void k_init(const float* __restrict__ W, float* __restrict__ C, int* __restrict__ done) {
  int i = blockIdx.x * 256 + threadIdx.x;
  C[i] = W[i];
  if (i == 0) *done = 0;
}

// ---------------- row norms of W (wave per row) ----------------
__global__ void k_w2(const float* __restrict__ W, float* __restrict__ w2) {
  int row  = blockIdx.x * 4 + (threadIdx.x >> 6);
  int lane = threadIdx.x & 63;
  float4 v = *(const float4*)(W + (size_t)row * DIM + 4 * lane);
  float s = v.x*v.x + v.y*v.y + v.z*v.z + v.w*v.w;
  #pragma unroll
  for (int o = 32; o; o >>= 1) s += __shfl_down(s, o);
  if (lane == 0) w2[row] = s;
}

// ---------------- per-iter prep: c2, zero wsum/counts ----------------
__global__ void k_prep(const float* __restrict__ C, float* __restrict__ c2,
                       float* __restrict__ wsum, float* __restrict__ counts) {
  __shared__ float wsh[4];
  int b = blockIdx.x, t = threadIdx.x;
  float v = C[b * DIM + t];
  float s = v * v;
  #pragma unroll
  for (int o = 32; o; o >>= 1) s += __shfl_down(s, o);
  if ((t & 63) == 0) wsh[t >> 6] = s;
  __syncthreads();
  if (t == 0) c2[b] = wsh[0] + wsh[1] + wsh[2] + wsh[3];
  wsum[b * DIM + t] = 0.f;
  if (t == 0) counts[b] = 0.f;
}

// ---------------- fused distances + softmax + counts ----------------
#define A_BM 32
#define A_KC 32
__launch_bounds__(256, 2)
__global__ void k_attn(const float* __restrict__ W, const float* __restrict__ C,
                       const float* __restrict__ w2, const float* __restrict__ c2,
                       float* __restrict__ attn, float* __restrict__ counts,
                       const int* __restrict__ done)
{
  if (*done) return;
  __shared__ float Wt[DIM * A_BM];      // [k][32 rows] swizzled (32 KB)
  __shared__ float Ct[A_KC * 64];       // [k][64 cols] swizzled (8 KB)
  __shared__ float red[64 * 16];        // reduction scratch (4 KB)
  __shared__ float rowSum[A_BM], w2s[A_BM], c2s[64], rinv[A_BM];

  const int t  = threadIdx.x;
  const int tx = t & 15;
  const int ty = t >> 4;
  const int rowbase = blockIdx.x * A_BM;

  // stage Wt: 32 rows x 256 k, transpose+swizzle
  #pragma unroll
  for (int p = 0; p < 8; ++p) {
    int q  = p * 256 + t;             // [r:32][d4:64]
    int r  = q >> 6;
    int d4 = q & 63;
    float4 v = *(const float4*)(W + (size_t)(rowbase + r) * DIM + 4 * d4);
    Wt[swz32(4*d4+0, r)] = v.x;
    Wt[swz32(4*d4+1, r)] = v.y;
    Wt[swz32(4*d4+2, r)] = v.z;
    Wt[swz32(4*d4+3, r)] = v.w;
  }
  if (t < A_BM) { w2s[t] = w2[rowbase + t]; rowSum[t] = 0.f; }

  float e[8][2][4];   // unnormalized exp scores, all 512 clusters

  #pragma unroll
  for (int ct = 0; ct < 8; ++ct) {
    float acc[2][4] = {{0.f,0.f,0.f,0.f},{0.f,0.f,0.f,0.f}};
    for (int kc = 0; kc < 8; ++kc) {
      __syncthreads();
      #pragma unroll
      for (int p = 0; p < 2; ++p) {
        int q  = p * 256 + t;         // [c:64][d4:8]
        int c  = q >> 3;
        int d4 = q & 7;
        float4 v = *(const float4*)(C + (size_t)(ct*64 + c) * DIM + kc*A_KC + 4*d4);
        Ct[swz64(4*d4+0, c)] = v.x;
        Ct[swz64(4*d4+1, c)] = v.y;
        Ct[swz64(4*d4+2, c)] = v.z;
        Ct[swz64(4*d4+3, c)] = v.w;
      }
      if (kc == 0 && t < 64) c2s[t] = c2[ct*64 + t];
      __syncthreads();
      #pragma unroll 8
      for (int k = 0; k < A_KC; ++k) {
        float2 wv = *(const float2*)&Wt[swz32(kc*A_KC + k, 2*ty)];
        float4 cv = *(const float4*)&Ct[swz64(k, 4*tx)];
        acc[0][0] += wv.x*cv.x; acc[0][1] += wv.x*cv.y;
        acc[0][2] += wv.x*cv.z; acc[0][3] += wv.x*cv.w;
        acc[1][0] += wv.y*cv.x; acc[1][1] += wv.y*cv.y;
        acc[1][2] += wv.y*cv.z; acc[1][3] += wv.y*cv.w;
      }
    }
    float ps[2];
    #pragma unroll
    for (int i = 0; i < 2; ++i) {
      float s = 0.f;
      #pragma unroll
      for (int j = 0; j < 4; ++j) {
        float d2 = w2s[2*ty+i] + c2s[4*tx+j] - 2.f * acc[i][j];
        float sc = -sqrtf(fmaxf(d2, 1e-12f));       // TEMPERATURE == 1
        float ev = expf(sc);                        // scores in [-30,0]: no underflow
        e[ct][i][j] = ev;
        s += ev;
      }
      ps[i] = s;
    }
    __syncthreads();
    red[(2*ty+0)*16 + tx] = ps[0];
    red[(2*ty+1)*16 + tx] = ps[1];
    __syncthreads();
    if (t < A_BM) {
      float s = 0.f;
      #pragma unroll
      for (int x = 0; x < 16; ++x) s += red[t*16 + x];
      rowSum[t] += s;
    }
  }
  __syncthreads();
  if (t < A_BM) rinv[t] = 1.0f / rowSum[t];
  __syncthreads();

  // pass 2: normalize, store attn, accumulate counts
  #pragma unroll
  for (int ct = 0; ct < 8; ++ct) {
    float cp[4] = {0.f,0.f,0.f,0.f};
    #pragma unroll
    for (int i = 0; i < 2; ++i) {
      float ri = rinv[2*ty+i];
      float4 av;
      av.x = e[ct][i][0]*ri; av.y = e[ct][i][1]*ri;
      av.z = e[ct][i][2]*ri; av.w = e[ct][i][3]*ri;
      cp[0] += av.x; cp[1] += av.y; cp[2] += av.z; cp[3] += av.w;
      *(float4*)(attn + (size_t)(rowbase + 2*ty + i) * NC + ct*64 + 4*tx) = av;
    }
    __syncthreads();
    #pragma unroll
    for (int j = 0; j < 4; ++j) red[(4*tx+j)*16 + ty] = cp[j];
    __syncthreads();
    if (t < 64) {
      float s = 0.f;
      #pragma unroll
      for (int x = 0; x < 16; ++x) s += red[t*16 + x];
      atomicAdd(&counts[ct*64 + t], s);
    }
  }
}

// ---------------- wsum = attn^T @ W (K-split, atomic epilogue) ----------------
__launch_bounds__(256, 2)
__global__ void k_wsum(const float* __restrict__ attn, const float* __restrict__ W,
                       float* __restrict__ wsum, const int* __restrict__ done)
{
  if (*done) return;
  __shared__ float At[64*64];   // [k][64 c] (16 KB)
  __shared__ float Bt[64*64];   // [k][64 d] (16 KB)
  const int t = threadIdx.x, tx = t & 15, ty = t >> 4;
  const int ctile = blockIdx.x & 7;
  const int dtile = (blockIdx.x >> 3) & 3;
  const int kch   = blockIdx.x >> 5;          // 32 chunks of 2048 rows
  const int c0 = ctile*64, d0 = dtile*64;
  const size_t rbase = (size_t)kch * 2048;
  float acc[4][4] = {{0}};
  for (int kk = 0; kk < 2048; kk += 64) {
    __syncthreads();
    #pragma unroll
    for (int p = 0; p < 4; ++p) {
      int q = p*256 + t;
      int kr = q >> 4, c4 = q & 15;
      size_t row = rbase + kk + kr;
      *(float4*)&At[kr*64 + 4*c4] = *(const float4*)(attn + row*NC  + c0 + 4*c4);
      *(float4*)&Bt[kr*64 + 4*c4] = *(const float4*)(W    + row*DIM + d0 + 4*c4);
    }
    __syncthreads();
    #pragma unroll 8
    for (int k = 0; k < 64; ++k) {
      float4 av = *(const float4*)&At[k*64 + 4*ty];
      float4 bv = *(const float4*)&Bt[k*64 + 4*tx];
      acc[0][0]+=av.x*bv.x; acc[0][1]+=av.x*bv.y; acc[0][2]+=av.x*bv.z; acc[0][3]+=av.x*bv.w;
      acc[1][0]+=av.y*bv.x; acc[1][1]+=av.y*bv.y; acc[1][2]+=av.y*bv.z; acc[1][3]+=av.y*bv.w;
      acc[2][0]+=av.z*bv.x; acc[2][1]+=av.z*bv.y; acc[2][2]+=av.z*bv.z; acc[2][3]+=av.z*bv.w;
      acc[3][0]+=av.w*bv.x; acc[3][1]+=av.w*bv.y; acc[3][2]+=av.w*bv.z; acc[3][3]+=av.w*bv.w;
    }
  }
  #pragma unroll
  for (int i = 0; i < 4; ++i)
    #pragma unroll
    for (int j = 0; j < 4; ++j)
      atomicAdd(&wsum[(size_t)(c0 + 4*ty + i)*DIM + d0 + 4*tx + j], acc[i][j]);
}

// ---------------- cluster update + convergence ----------------
__global__ void k_update(float* __restrict__ C, const float* __restrict__ wsum,
                         const float* __restrict__ counts, int* __restrict__ done)
{
  if (*done) return;
  __shared__ float wsh[16];
  __shared__ float nrm2;
  int t = threadIdx.x;  // 1024
  float local = 0.f;
  for (int p = 0; p < 128; ++p) {
    int i = p*1024 + t;
    float cn = wsum[i] / counts[i >> 8];
    float d  = C[i] - cn;
    local += d * d;
  }
  #pragma unroll
  for (int o = 32; o; o >>= 1) local += __shfl_down(local, o);
  if ((t & 63) == 0) wsh[t >> 6] = local;
  __syncthreads();
  if (t == 0) {
    float s = 0.f;
    #pragma unroll
    for (int x = 0; x < 16; ++x) s += wsh[x];
    nrm2 = s;
  }
  __syncthreads();
  if (nrm2 <= 1e-8f) {              // norm <= 1e-4  -> keep old clusters, mark done
    if (t == 0) *done = 1;
  } else {
    for (int p = 0; p < 128; ++p) {
      int i = p*1024 + t;
      C[i] = wsum[i] / counts[i >> 8];
    }
  }
}

// ---------------- compressed = attn @ C ----------------
__launch_bounds__(256, 2)
__global__ void k_compress(const float* __restrict__ attn, const float* __restrict__ C,
                           float* __restrict__ out)
{
  __shared__ float At[64*64];   // [k][64 r] swizzled
  __shared__ float Bt[64*64];   // [k][64 d]
  const int t = threadIdx.x, tx = t & 15, ty = t >> 4;
  const int rt = blockIdx.x >> 2;
  const int dt = blockIdx.x & 3;
  const int r0 = rt*64, d0 = dt*64;
  float acc[4][4] = {{0}};
  for (int kc = 0; kc < 8; ++kc) {
    __syncthreads();
    #pragma unroll
    for (int p = 0; p < 4; ++p) {
      int q = p*256 + t;
      int r = q >> 4, x4 = q & 15;
      float4 v = *(const float4*)(attn + (size_t)(r0 + r)*NC + kc*64 + 4*x4);
      At[swz64(4*x4+0, r)] = v.x;
      At[swz64(4*x4+1, r)] = v.y;
      At[swz64(4*x4+2, r)] = v.z;
      At[swz64(4*x4+3, r)] = v.w;
      *(float4*)&Bt[r*64 + 4*x4] = *(const float4*)(C + (size_t)(kc*64 + r)*DIM + d0 + 4*x4);
    }
    __syncthreads();
    #pragma unroll 8
    for (int k = 0; k < 64; ++k) {
      float4 av = *(const float4*)&At[swz64(k, 4*ty)];
      float4 bv = *(const float4*)&Bt[k*64 + 4*tx];
      acc[0][0]+=av.x*bv.x; acc[0][1]+=av.x*bv.y; acc[0][2]+=av.x*bv.z; acc[0][3]+=av.x*bv.w;
      acc[1][0]+=av.y*bv.x; acc[1][1]+=av.y*bv.y; acc[1][2]+=av.y*bv.z; acc[1][3]+=av.y*bv.w;
      acc[2][0]+=av.z*bv.x; acc[2][1]+=av.z*bv.y; acc[2][2]+=av.z*bv.z; acc[2][3]+=av.z*bv.w;
      acc[3][0]+=av.w*bv.x; acc[3][1]+=av.w*bv.y; acc[3][2]+=av.w*bv.z; acc[3][3]+=av.w*bv.w;
    }
  }
  #pragma unroll
  for (int i = 0; i < 4; ++i) {
    float4 o = {acc[i][0], acc[i][1], acc[i][2], acc[i][3]};
    *(float4*)(out + (size_t)(r0 + 4*ty + i)*DIM + d0 + 4*tx) = o;
  }
}

__global__ void k_copy(const float* __restrict__ C, float* __restrict__ out) {
  int i = blockIdx.x * 256 + threadIdx.x;
  out[i] = C[i];
}

extern "C" void kernel_launch(void* const* d_in, const int* in_sizes, int n_in,
                              void* d_out, int out_size, void* d_ws, size_t ws_size,
                              hipStream_t stream)
{
  const float* W = (const float*)d_in[0];
  float* out = (float*)d_out;
  float* compressed   = out;                               // 65536*256
  float* out_clusters = out + (size_t)NPTS * DIM;          // 512*256
  float* attn         = out_clusters + NC * DIM;           // 65536*512

  float* ws    = (float*)d_ws;
  float* C      = ws + WS_C;
  float* wsum   = ws + WS_WSUM;
  float* counts = ws + WS_COUNTS;
  float* w2     = ws + WS_W2;
  float* c2     = ws + WS_C2;
  int*   done   = (int*)(ws + WS_DONE);

  k_init<<<NC*DIM/256, 256, 0, stream>>>(W, C, done);
  k_w2<<<NPTS/4, 256, 0, stream>>>(W, w2);
  for (int it = 0; it < NITER; ++it) {
    k_prep<<<NC, 256, 0, stream>>>(C, c2, wsum, counts);
    k_attn<<<NPTS/A_BM, 256, 0, stream>>>(W, C, w2, c2, attn, counts, done);
    k_wsum<<<1024, 256, 0, stream>>>(attn, W, wsum, done);
    k_update<<<1, 1024, 0, stream>>>(C, wsum, counts, done);
  }
  k_compress<<<(NPTS/64)*(DIM/64), 256, 0, stream>>>(attn, C, compressed);
  k_copy<<<NC*DIM/256, 256, 0, stream>>>(C, out_clusters);
}